// Round 2
// baseline (3272.035 us; speedup 1.0000x reference)
//
#include <hip/hip_runtime.h>
#include <math.h>

#define N_NODES 100000
#define N_EDGES 1600000
#define NB 64
#define F_IN 128
#define HDIM 64
#define NC 10

// ---------- float <-> order-preserving uint ----------
__device__ __forceinline__ unsigned fenc(float f) {
    unsigned u = __float_as_uint(f);
    return (u & 0x80000000u) ? ~u : (u | 0x80000000u);
}
__device__ __forceinline__ float fdec(unsigned u) {
    unsigned bits = (u & 0x80000000u) ? (u ^ 0x80000000u) : ~u;
    return __uint_as_float(bits);
}

// ---------- fused q/k/v/skip GEMM:  out = x @ W^T + b  ----------
// grid.x = ceil(N/64), grid.y = 4 (mat select), block = 256
template<int K>
__global__ __launch_bounds__(256) void qkvs_gemm(
    const float* __restrict__ xin,
    const float* __restrict__ Wq, const float* __restrict__ bq,
    const float* __restrict__ Wk, const float* __restrict__ bk,
    const float* __restrict__ Wv, const float* __restrict__ bv,
    const float* __restrict__ Ws, const float* __restrict__ bs,
    float* __restrict__ q, float* __restrict__ k,
    float* __restrict__ v, float* __restrict__ sk)
{
    __shared__ float Xs[32][68];   // transposed: Xs[k][row]
    __shared__ float Wt[32][68];   // transposed: Wt[k][col]

    const float* W; const float* b; float* out;
    switch (blockIdx.y) {
        case 0: W = Wq; b = bq; out = q;  break;
        case 1: W = Wk; b = bk; out = k;  break;
        case 2: W = Wv; b = bv; out = v;  break;
        default: W = Ws; b = bs; out = sk; break;
    }

    const int row0 = blockIdx.x * 64;
    const int tid  = threadIdx.x;
    const int tc   = tid & 15;   // col group (4 cols each)
    const int tr   = tid >> 4;   // row group (4 rows each)

    float acc[4][4] = {};

    const int lrow = tid >> 2;        // 0..63
    const int lk   = (tid & 3) * 8;   // 0,8,16,24

    for (int k0 = 0; k0 < K; k0 += 32) {
        // stage X tile (64 rows x 32 k) transposed
        {
            int grow = row0 + lrow;
            float tmp[8];
            if (grow < N_NODES) {
                const float* p = xin + (size_t)grow * K + k0 + lk;
                float4 a = *(const float4*)p;
                float4 c = *(const float4*)(p + 4);
                tmp[0]=a.x; tmp[1]=a.y; tmp[2]=a.z; tmp[3]=a.w;
                tmp[4]=c.x; tmp[5]=c.y; tmp[6]=c.z; tmp[7]=c.w;
            } else {
                #pragma unroll
                for (int i = 0; i < 8; i++) tmp[i] = 0.f;
            }
            #pragma unroll
            for (int i = 0; i < 8; i++) Xs[lk + i][lrow] = tmp[i];

            const float* pw = W + (size_t)lrow * K + k0 + lk;
            float4 a = *(const float4*)pw;
            float4 c = *(const float4*)(pw + 4);
            float wt[8] = {a.x, a.y, a.z, a.w, c.x, c.y, c.z, c.w};
            #pragma unroll
            for (int i = 0; i < 8; i++) Wt[lk + i][lrow] = wt[i];
        }
        __syncthreads();

        #pragma unroll 8
        for (int kk = 0; kk < 32; kk++) {
            float4 xf = *(const float4*)&Xs[kk][tr * 4];
            float4 wf = *(const float4*)&Wt[kk][tc * 4];
            float xa[4] = {xf.x, xf.y, xf.z, xf.w};
            float wa[4] = {wf.x, wf.y, wf.z, wf.w};
            #pragma unroll
            for (int i = 0; i < 4; i++)
                #pragma unroll
                for (int j = 0; j < 4; j++)
                    acc[i][j] += xa[i] * wa[j];
        }
        __syncthreads();
    }

    float4 bias = *(const float4*)&b[tc * 4];
    float ba[4] = {bias.x, bias.y, bias.z, bias.w};
    #pragma unroll
    for (int i = 0; i < 4; i++) {
        int grow = row0 + tr * 4 + i;
        if (grow < N_NODES) {
            float4 r;
            r.x = acc[i][0] + ba[0];
            r.y = acc[i][1] + ba[1];
            r.z = acc[i][2] + ba[2];
            r.w = acc[i][3] + ba[3];
            *(float4*)&out[(size_t)grow * HDIM + tc * 4] = r;
        }
    }
}

// ---------- edge pass 1: alpha + segment max (wave per edge) ----------
__global__ __launch_bounds__(256) void edge_alpha(
    const int* __restrict__ ei,
    const float* __restrict__ q, const float* __restrict__ k,
    float* __restrict__ alpha, unsigned* __restrict__ m)
{
    int e = blockIdx.x * 4 + (threadIdx.x >> 6);
    if (e >= N_EDGES) return;
    int lane = threadIdx.x & 63;
    int src = ei[e];
    int dst = ei[N_EDGES + e];
    float p = q[(size_t)dst * HDIM + lane] * k[(size_t)src * HDIM + lane];
    #pragma unroll
    for (int off = 32; off; off >>= 1) p += __shfl_xor(p, off, 64);
    if (lane == 0) {
        float a = p * 0.125f;   // / sqrt(64)
        alpha[e] = a;
        atomicMax(&m[dst], fenc(a));
    }
}

// ---------- edge pass 2: exp + scatter numerator/denominator ----------
__global__ __launch_bounds__(256) void edge_scatter(
    const int* __restrict__ ei,
    const float* __restrict__ alpha, const unsigned* __restrict__ m,
    const float* __restrict__ v,
    float* __restrict__ s, float* __restrict__ agg)
{
    int e = blockIdx.x * 4 + (threadIdx.x >> 6);
    if (e >= N_EDGES) return;
    int lane = threadIdx.x & 63;
    int src = ei[e];
    int dst = ei[N_EDGES + e];
    float mx = fdec(m[dst]);
    float ee = __expf(alpha[e] - mx);
    if (lane == 0) atomicAdd(&s[dst], ee);
    atomicAdd(&agg[(size_t)dst * HDIM + lane], ee * v[(size_t)src * HDIM + lane]);
}

// ---------- node finalize: h = [relu](agg/s + skip) ----------
__global__ __launch_bounds__(256) void finalize_node(
    const float* __restrict__ agg, const float* __restrict__ s,
    const float* __restrict__ skip, float* __restrict__ hout, int do_relu)
{
    int idx = blockIdx.x * 256 + threadIdx.x;
    if (idx >= N_NODES * HDIM) return;
    int n = idx >> 6;
    float sv = s[n];
    float val = (sv > 0.f ? agg[idx] / sv : 0.f) + skip[idx];
    if (do_relu) val = fmaxf(val, 0.f);
    hout[idx] = val;
}

// ---------- mean pool (atomic) ----------
__global__ __launch_bounds__(256) void pool_kernel(
    const float* __restrict__ h, const int* __restrict__ batch,
    float* __restrict__ sums, float* __restrict__ cnt)
{
    int n = blockIdx.x * 4 + (threadIdx.x >> 6);
    if (n >= N_NODES) return;
    int lane = threadIdx.x & 63;
    int b = batch[n];
    atomicAdd(&sums[b * HDIM + lane], h[(size_t)n * HDIM + lane]);
    if (lane == 0) atomicAdd(&cnt[b], 1.0f);
}

// ---------- head: out = (sums/cnt) @ Wl^T + bl ----------
__global__ void head_kernel(
    const float* __restrict__ sums, const float* __restrict__ cnt,
    const float* __restrict__ Wl, const float* __restrict__ bl,
    float* __restrict__ out)
{
    int tid = threadIdx.x;
    if (tid >= NB * NC) return;
    int b = tid / NC, c = tid % NC;
    float cc = fmaxf(cnt[b], 1.0f);
    float acc = bl[c];
    #pragma unroll
    for (int f = 0; f < HDIM; f++)
        acc += (sums[b * HDIM + f] / cc) * Wl[c * HDIM + f];
    out[tid] = acc;
}

extern "C" void kernel_launch(void* const* d_in, const int* in_sizes, int n_in,
                              void* d_out, int out_size, void* d_ws, size_t ws_size,
                              hipStream_t stream)
{
    const float* x     = (const float*)d_in[0];
    const int*   ei    = (const int*)d_in[1];
    const int*   batch = (const int*)d_in[2];

    const float* W[3][4];
    const float* B[3][4];
    for (int l = 0; l < 3; l++)
        for (int j = 0; j < 4; j++) {
            W[l][j] = (const float*)d_in[3 + l * 8 + j * 2];
            B[l][j] = (const float*)d_in[3 + l * 8 + j * 2 + 1];
        }
    const float* Wl = (const float*)d_in[27];
    const float* bl = (const float*)d_in[28];
    float* out = (float*)d_out;

    const size_t NF = (size_t)N_NODES * HDIM;
    char* w = (char*)d_ws;
    float*    h     = (float*)w;    w += NF * 4;
    float*    q     = (float*)w;    w += NF * 4;   // aliased as agg after edge_alpha
    float*    kbuf  = (float*)w;    w += NF * 4;
    float*    v     = (float*)w;    w += NF * 4;
    float*    skip  = (float*)w;    w += NF * 4;
    float*    alpha = (float*)w;    w += (size_t)N_EDGES * 4;
    unsigned* mbuf  = (unsigned*)w; w += (size_t)N_NODES * 4;
    float*    sden  = (float*)w;    w += (size_t)N_NODES * 4;
    float*    sums  = (float*)w;    w += (size_t)NB * HDIM * 4;
    float*    cnt   = (float*)w;    w += (size_t)NB * 4;

    float* agg = q;   // q dead after edge_alpha; reuse as aggregation buffer

    const int gemm_gx = (N_NODES + 63) / 64;
    const int edge_gx = N_EDGES / 4;
    const int node_gx = (int)((NF + 255) / 256);
    const int pool_gx = N_NODES / 4;

    for (int l = 0; l < 3; l++) {
        hipMemsetAsync(mbuf, 0, N_NODES * 4, stream);
        hipMemsetAsync(sden, 0, N_NODES * 4, stream);

        if (l == 0) {
            qkvs_gemm<F_IN><<<dim3(gemm_gx, 4), 256, 0, stream>>>(
                x, W[0][0], B[0][0], W[0][1], B[0][1],
                   W[0][2], B[0][2], W[0][3], B[0][3], q, kbuf, v, skip);
        } else {
            qkvs_gemm<HDIM><<<dim3(gemm_gx, 4), 256, 0, stream>>>(
                h, W[l][0], B[l][0], W[l][1], B[l][1],
                   W[l][2], B[l][2], W[l][3], B[l][3], q, kbuf, v, skip);
        }

        edge_alpha<<<edge_gx, 256, 0, stream>>>(ei, q, kbuf, alpha, mbuf);
        hipMemsetAsync(agg, 0, NF * 4, stream);   // after edge_alpha: q -> agg
        edge_scatter<<<edge_gx, 256, 0, stream>>>(ei, alpha, mbuf, v, sden, agg);
        finalize_node<<<node_gx, 256, 0, stream>>>(agg, sden, skip, h, l < 2 ? 1 : 0);
    }

    hipMemsetAsync(sums, 0, NB * HDIM * 4, stream);
    hipMemsetAsync(cnt,  0, NB * 4, stream);
    pool_kernel<<<pool_gx, 256, 0, stream>>>(h, batch, sums, cnt);
    head_kernel<<<1, 640, 0, stream>>>(sums, cnt, Wl, bl, out);
}

// Round 3
// 1277.915 us; speedup vs baseline: 2.5604x; 2.5604x over previous
//
#include <hip/hip_runtime.h>
#include <math.h>

#define N_NODES 100000
#define N_EDGES 1600000
#define NB 64
#define F_IN 128
#define HDIM 64
#define NC 10
#define SCAN_T 1024

// ---------- fused q/k/v/skip GEMM:  out = x @ W^T + b  ----------
// grid.x = ceil(N/64), grid.y = 4 (mat select), block = 256
template<int K>
__global__ __launch_bounds__(256) void qkvs_gemm(
    const float* __restrict__ xin,
    const float* __restrict__ Wq, const float* __restrict__ bq,
    const float* __restrict__ Wk, const float* __restrict__ bk,
    const float* __restrict__ Wv, const float* __restrict__ bv,
    const float* __restrict__ Ws, const float* __restrict__ bs,
    float* __restrict__ q, float* __restrict__ k,
    float* __restrict__ v, float* __restrict__ sk)
{
    __shared__ float Xs[32][68];   // transposed: Xs[k][row]
    __shared__ float Wt[32][68];   // transposed: Wt[k][col]

    const float* W; const float* b; float* out;
    switch (blockIdx.y) {
        case 0: W = Wq; b = bq; out = q;  break;
        case 1: W = Wk; b = bk; out = k;  break;
        case 2: W = Wv; b = bv; out = v;  break;
        default: W = Ws; b = bs; out = sk; break;
    }

    const int row0 = blockIdx.x * 64;
    const int tid  = threadIdx.x;
    const int tc   = tid & 15;   // col group (4 cols each)
    const int tr   = tid >> 4;   // row group (4 rows each)

    float acc[4][4] = {};

    const int lrow = tid >> 2;        // 0..63
    const int lk   = (tid & 3) * 8;   // 0,8,16,24

    for (int k0 = 0; k0 < K; k0 += 32) {
        {
            int grow = row0 + lrow;
            float tmp[8];
            if (grow < N_NODES) {
                const float* p = xin + (size_t)grow * K + k0 + lk;
                float4 a = *(const float4*)p;
                float4 c = *(const float4*)(p + 4);
                tmp[0]=a.x; tmp[1]=a.y; tmp[2]=a.z; tmp[3]=a.w;
                tmp[4]=c.x; tmp[5]=c.y; tmp[6]=c.z; tmp[7]=c.w;
            } else {
                #pragma unroll
                for (int i = 0; i < 8; i++) tmp[i] = 0.f;
            }
            #pragma unroll
            for (int i = 0; i < 8; i++) Xs[lk + i][lrow] = tmp[i];

            const float* pw = W + (size_t)lrow * K + k0 + lk;
            float4 a = *(const float4*)pw;
            float4 c = *(const float4*)(pw + 4);
            float wt[8] = {a.x, a.y, a.z, a.w, c.x, c.y, c.z, c.w};
            #pragma unroll
            for (int i = 0; i < 8; i++) Wt[lk + i][lrow] = wt[i];
        }
        __syncthreads();

        #pragma unroll 8
        for (int kk = 0; kk < 32; kk++) {
            float4 xf = *(const float4*)&Xs[kk][tr * 4];
            float4 wf = *(const float4*)&Wt[kk][tc * 4];
            float xa[4] = {xf.x, xf.y, xf.z, xf.w};
            float wa[4] = {wf.x, wf.y, wf.z, wf.w};
            #pragma unroll
            for (int i = 0; i < 4; i++)
                #pragma unroll
                for (int j = 0; j < 4; j++)
                    acc[i][j] += xa[i] * wa[j];
        }
        __syncthreads();
    }

    float4 bias = *(const float4*)&b[tc * 4];
    float ba[4] = {bias.x, bias.y, bias.z, bias.w};
    #pragma unroll
    for (int i = 0; i < 4; i++) {
        int grow = row0 + tr * 4 + i;
        if (grow < N_NODES) {
            float4 r;
            r.x = acc[i][0] + ba[0];
            r.y = acc[i][1] + ba[1];
            r.z = acc[i][2] + ba[2];
            r.w = acc[i][3] + ba[3];
            *(float4*)&out[(size_t)grow * HDIM + tc * 4] = r;
        }
    }
}

// ---------- CSR build: degree histogram ----------
__global__ __launch_bounds__(256) void count_deg(
    const int* __restrict__ ei, int* __restrict__ deg)
{
    int e = blockIdx.x * 256 + threadIdx.x;
    if (e >= N_EDGES) return;
    atomicAdd(&deg[ei[N_EDGES + e]], 1);
}

// ---------- CSR build: single-block exclusive scan over deg ----------
__global__ __launch_bounds__(SCAN_T) void scan_deg(
    const int* __restrict__ deg, int* __restrict__ row_ptr, int* __restrict__ cursor)
{
    __shared__ int part[SCAN_T];
    const int tid = threadIdx.x;
    const int chunk = (N_NODES + SCAN_T - 1) / SCAN_T;
    const int b = tid * chunk;
    const int e = min(b + chunk, N_NODES);
    int sum = 0;
    for (int i = b; i < e; i++) sum += deg[i];
    part[tid] = sum;
    __syncthreads();
    for (int off = 1; off < SCAN_T; off <<= 1) {
        int t = (tid >= off) ? part[tid - off] : 0;
        __syncthreads();
        part[tid] += t;
        __syncthreads();
    }
    int run = part[tid] - sum;   // exclusive prefix of this chunk
    for (int i = b; i < e; i++) {
        row_ptr[i] = run; cursor[i] = run;
        run += deg[i];
    }
    if (e == N_NODES) row_ptr[N_NODES] = run;
}

// ---------- CSR build: scatter src into slots ----------
__global__ __launch_bounds__(256) void scatter_csr(
    const int* __restrict__ ei, int* __restrict__ cursor, int* __restrict__ csr_src)
{
    int e = blockIdx.x * 256 + threadIdx.x;
    if (e >= N_EDGES) return;
    int src = ei[e];
    int dst = ei[N_EDGES + e];
    int pos = atomicAdd(&cursor[dst], 1);
    csr_src[pos] = src;
}

// ---------- fused attention: per-dst online softmax + skip + relu ----------
// wave = one dst node, lane = feature
__global__ __launch_bounds__(256) void attn_fused(
    const int* __restrict__ row_ptr, const int* __restrict__ csr_src,
    const float* __restrict__ q, const float* __restrict__ k,
    const float* __restrict__ v, const float* __restrict__ skip,
    float* __restrict__ hout, int do_relu)
{
    int n = blockIdx.x * 4 + (threadIdx.x >> 6);
    if (n >= N_NODES) return;
    int lane = threadIdx.x & 63;
    int beg = row_ptr[n], end = row_ptr[n + 1];
    float qf = q[(size_t)n * HDIM + lane];
    float m = -1e30f, s = 0.f, acc = 0.f;
    for (int i = beg; i < end; i++) {
        int src = csr_src[i];
        float kf = k[(size_t)src * HDIM + lane];
        float vf = v[(size_t)src * HDIM + lane];
        float p = qf * kf;
        #pragma unroll
        for (int off = 32; off; off >>= 1) p += __shfl_xor(p, off, 64);
        float a = p * 0.125f;   // / sqrt(64)
        if (a > m) {
            float sc = __expf(m - a);
            s *= sc; acc *= sc; m = a;
        }
        float e = __expf(a - m);
        s += e; acc += e * vf;
    }
    float val = (s > 0.f ? acc / s : 0.f) + skip[(size_t)n * HDIM + lane];
    if (do_relu) val = fmaxf(val, 0.f);
    hout[(size_t)n * HDIM + lane] = val;
}

// ---------- mean pool: run-length accumulate (batch sorted) ----------
__global__ __launch_bounds__(256) void pool_kernel(
    const float* __restrict__ h, const int* __restrict__ batch,
    float* __restrict__ sums, float* __restrict__ cnt)
{
    int wid = blockIdx.x * 4 + (threadIdx.x >> 6);
    int n0 = wid * 64;
    if (n0 >= N_NODES) return;
    int lane = threadIdx.x & 63;
    int nend = min(n0 + 64, N_NODES);
    float acc = 0.f;
    int b_cur = batch[n0];
    int run = 0;
    for (int n = n0; n < nend; n++) {
        int b = batch[n];
        if (b != b_cur) {
            atomicAdd(&sums[b_cur * HDIM + lane], acc);
            if (lane == 0) atomicAdd(&cnt[b_cur], (float)run);
            acc = 0.f; run = 0; b_cur = b;
        }
        acc += h[(size_t)n * HDIM + lane];
        run++;
    }
    atomicAdd(&sums[b_cur * HDIM + lane], acc);
    if (lane == 0) atomicAdd(&cnt[b_cur], (float)run);
}

// ---------- head: out = (sums/cnt) @ Wl^T + bl ----------
__global__ void head_kernel(
    const float* __restrict__ sums, const float* __restrict__ cnt,
    const float* __restrict__ Wl, const float* __restrict__ bl,
    float* __restrict__ out)
{
    int tid = threadIdx.x;
    if (tid >= NB * NC) return;
    int b = tid / NC, c = tid % NC;
    float cc = fmaxf(cnt[b], 1.0f);
    float acc = bl[c];
    #pragma unroll
    for (int f = 0; f < HDIM; f++)
        acc += (sums[b * HDIM + f] / cc) * Wl[c * HDIM + f];
    out[tid] = acc;
}

extern "C" void kernel_launch(void* const* d_in, const int* in_sizes, int n_in,
                              void* d_out, int out_size, void* d_ws, size_t ws_size,
                              hipStream_t stream)
{
    const float* x     = (const float*)d_in[0];
    const int*   ei    = (const int*)d_in[1];
    const int*   batch = (const int*)d_in[2];

    const float* W[3][4];
    const float* B[3][4];
    for (int l = 0; l < 3; l++)
        for (int j = 0; j < 4; j++) {
            W[l][j] = (const float*)d_in[3 + l * 8 + j * 2];
            B[l][j] = (const float*)d_in[3 + l * 8 + j * 2 + 1];
        }
    const float* Wl = (const float*)d_in[27];
    const float* bl = (const float*)d_in[28];
    float* out = (float*)d_out;

    const size_t NF = (size_t)N_NODES * HDIM;
    char* w = (char*)d_ws;
    float* h       = (float*)w;  w += NF * 4;
    float* q       = (float*)w;  w += NF * 4;
    float* kbuf    = (float*)w;  w += NF * 4;
    float* v       = (float*)w;  w += NF * 4;
    float* skip    = (float*)w;  w += NF * 4;
    int*   csr_src = (int*)w;    w += (size_t)N_EDGES * 4;
    int*   row_ptr = (int*)w;    w += (size_t)(N_NODES + 1) * 4;
    int*   cursor  = (int*)w;    w += (size_t)N_NODES * 4;
    int*   deg     = (int*)w;    w += (size_t)N_NODES * 4;
    float* sums    = (float*)w;  w += (size_t)NB * HDIM * 4;
    float* cnt     = (float*)w;  w += (size_t)NB * 4;

    const int gemm_gx = (N_NODES + 63) / 64;
    const int edge_gx = (N_EDGES + 255) / 256;
    const int node_gx = (N_NODES + 3) / 4;
    const int pool_gx = (N_NODES + 64 * 4 - 1) / (64 * 4);

    // ----- CSR build (once; edges shared by all 3 layers) -----
    hipMemsetAsync(deg, 0, (size_t)N_NODES * 4, stream);
    count_deg<<<edge_gx, 256, 0, stream>>>(ei, deg);
    scan_deg<<<1, SCAN_T, 0, stream>>>(deg, row_ptr, cursor);
    scatter_csr<<<edge_gx, 256, 0, stream>>>(ei, cursor, csr_src);

    for (int l = 0; l < 3; l++) {
        if (l == 0) {
            qkvs_gemm<F_IN><<<dim3(gemm_gx, 4), 256, 0, stream>>>(
                x, W[0][0], B[0][0], W[0][1], B[0][1],
                   W[0][2], B[0][2], W[0][3], B[0][3], q, kbuf, v, skip);
        } else {
            qkvs_gemm<HDIM><<<dim3(gemm_gx, 4), 256, 0, stream>>>(
                h, W[l][0], B[l][0], W[l][1], B[l][1],
                   W[l][2], B[l][2], W[l][3], B[l][3], q, kbuf, v, skip);
        }
        attn_fused<<<node_gx, 256, 0, stream>>>(
            row_ptr, csr_src, q, kbuf, v, skip, h, l < 2 ? 1 : 0);
    }

    hipMemsetAsync(sums, 0, (size_t)NB * HDIM * 4, stream);
    hipMemsetAsync(cnt,  0, (size_t)NB * 4, stream);
    pool_kernel<<<pool_gx, 256, 0, stream>>>(h, batch, sums, cnt);
    head_kernel<<<1, 640, 0, stream>>>(sums, cnt, Wl, bl, out);
}

// Round 4
// 851.279 us; speedup vs baseline: 3.8437x; 1.5012x over previous
//
#include <hip/hip_runtime.h>
#include <math.h>

#define N_NODES 100000
#define N_EDGES 1600000
#define NB 64
#define F_IN 128
#define HDIM 64
#define NC 10
#define NBLK_NODES ((N_NODES + 255) / 256)

// ---------- fused q/k/v/skip GEMM:  out = x @ W^T + b  ----------
template<int K>
__global__ __launch_bounds__(256) void qkvs_gemm(
    const float* __restrict__ xin,
    const float* __restrict__ Wq, const float* __restrict__ bq,
    const float* __restrict__ Wk, const float* __restrict__ bk,
    const float* __restrict__ Wv, const float* __restrict__ bv,
    const float* __restrict__ Ws, const float* __restrict__ bs,
    float* __restrict__ q, float* __restrict__ k,
    float* __restrict__ v, float* __restrict__ sk)
{
    __shared__ float Xs[32][68];   // transposed: Xs[k][row]
    __shared__ float Wt[32][68];   // transposed: Wt[k][col]

    const float* W; const float* b; float* out;
    switch (blockIdx.y) {
        case 0: W = Wq; b = bq; out = q;  break;
        case 1: W = Wk; b = bk; out = k;  break;
        case 2: W = Wv; b = bv; out = v;  break;
        default: W = Ws; b = bs; out = sk; break;
    }

    const int row0 = blockIdx.x * 64;
    const int tid  = threadIdx.x;
    const int tc   = tid & 15;
    const int tr   = tid >> 4;

    float acc[4][4] = {};

    const int lrow = tid >> 2;
    const int lk   = (tid & 3) * 8;

    for (int k0 = 0; k0 < K; k0 += 32) {
        {
            int grow = row0 + lrow;
            float tmp[8];
            if (grow < N_NODES) {
                const float* p = xin + (size_t)grow * K + k0 + lk;
                float4 a = *(const float4*)p;
                float4 c = *(const float4*)(p + 4);
                tmp[0]=a.x; tmp[1]=a.y; tmp[2]=a.z; tmp[3]=a.w;
                tmp[4]=c.x; tmp[5]=c.y; tmp[6]=c.z; tmp[7]=c.w;
            } else {
                #pragma unroll
                for (int i = 0; i < 8; i++) tmp[i] = 0.f;
            }
            #pragma unroll
            for (int i = 0; i < 8; i++) Xs[lk + i][lrow] = tmp[i];

            const float* pw = W + (size_t)lrow * K + k0 + lk;
            float4 a = *(const float4*)pw;
            float4 c = *(const float4*)(pw + 4);
            float wt[8] = {a.x, a.y, a.z, a.w, c.x, c.y, c.z, c.w};
            #pragma unroll
            for (int i = 0; i < 8; i++) Wt[lk + i][lrow] = wt[i];
        }
        __syncthreads();

        #pragma unroll 8
        for (int kk = 0; kk < 32; kk++) {
            float4 xf = *(const float4*)&Xs[kk][tr * 4];
            float4 wf = *(const float4*)&Wt[kk][tc * 4];
            float xa[4] = {xf.x, xf.y, xf.z, xf.w};
            float wa[4] = {wf.x, wf.y, wf.z, wf.w};
            #pragma unroll
            for (int i = 0; i < 4; i++)
                #pragma unroll
                for (int j = 0; j < 4; j++)
                    acc[i][j] += xa[i] * wa[j];
        }
        __syncthreads();
    }

    float4 bias = *(const float4*)&b[tc * 4];
    float ba[4] = {bias.x, bias.y, bias.z, bias.w};
    #pragma unroll
    for (int i = 0; i < 4; i++) {
        int grow = row0 + tr * 4 + i;
        if (grow < N_NODES) {
            float4 r;
            r.x = acc[i][0] + ba[0];
            r.y = acc[i][1] + ba[1];
            r.z = acc[i][2] + ba[2];
            r.w = acc[i][3] + ba[3];
            *(float4*)&out[(size_t)grow * HDIM + tc * 4] = r;
        }
    }
}

// ---------- CSR build ----------
__global__ __launch_bounds__(256) void count_deg(
    const int* __restrict__ ei, int* __restrict__ deg)
{
    int e = blockIdx.x * 256 + threadIdx.x;
    if (e >= N_EDGES) return;
    atomicAdd(&deg[ei[N_EDGES + e]], 1);
}

// per-block sums of deg (256 per block)
__global__ __launch_bounds__(256) void deg_block_sum(
    const int* __restrict__ deg, int* __restrict__ bsum)
{
    __shared__ int sh[256];
    int i = blockIdx.x * 256 + threadIdx.x;
    sh[threadIdx.x] = (i < N_NODES) ? deg[i] : 0;
    __syncthreads();
    #pragma unroll
    for (int off = 128; off; off >>= 1) {
        if (threadIdx.x < off) sh[threadIdx.x] += sh[threadIdx.x + off];
        __syncthreads();
    }
    if (threadIdx.x == 0) bsum[blockIdx.x] = sh[0];
}

// single small block: exclusive scan of block sums (nb <= 512)
__global__ __launch_bounds__(512) void scan_bsum(int* __restrict__ bsum, int nb)
{
    __shared__ int sh[512];
    int t = threadIdx.x;
    int v = (t < nb) ? bsum[t] : 0;
    sh[t] = v;
    __syncthreads();
    for (int off = 1; off < 512; off <<= 1) {
        int u = (t >= off) ? sh[t - off] : 0;
        __syncthreads();
        sh[t] += u;
        __syncthreads();
    }
    if (t < nb) bsum[t] = sh[t] - v;   // exclusive
}

// block-local scan + block prefix -> row_ptr / cursor
__global__ __launch_bounds__(256) void write_rowptr(
    const int* __restrict__ deg, const int* __restrict__ bsum,
    int* __restrict__ row_ptr, int* __restrict__ cursor)
{
    __shared__ int sh[256];
    int i = blockIdx.x * 256 + threadIdx.x;
    int v = (i < N_NODES) ? deg[i] : 0;
    sh[threadIdx.x] = v;
    __syncthreads();
    for (int off = 1; off < 256; off <<= 1) {
        int u = (threadIdx.x >= off) ? sh[threadIdx.x - off] : 0;
        __syncthreads();
        sh[threadIdx.x] += u;
        __syncthreads();
    }
    if (i < N_NODES) {
        int ex = bsum[blockIdx.x] + sh[threadIdx.x] - v;
        row_ptr[i] = ex;
        cursor[i] = ex;
        if (i == N_NODES - 1) row_ptr[N_NODES] = bsum[blockIdx.x] + sh[threadIdx.x];
    }
}

__global__ __launch_bounds__(256) void scatter_csr(
    const int* __restrict__ ei, int* __restrict__ cursor, int* __restrict__ csr_src)
{
    int e = blockIdx.x * 256 + threadIdx.x;
    if (e >= N_EDGES) return;
    int src = ei[e];
    int dst = ei[N_EDGES + e];
    int pos = atomicAdd(&cursor[dst], 1);
    csr_src[pos] = src;
}

// ---------- fused attention: per-dst online softmax + skip + relu ----------
// wave = one dst node, lane = feature; 2-edge unrolled, branchless merge
__global__ __launch_bounds__(256) void attn_fused(
    const int* __restrict__ row_ptr, const int* __restrict__ csr_src,
    const float* __restrict__ q, const float* __restrict__ k,
    const float* __restrict__ v, const float* __restrict__ skip,
    float* __restrict__ hout, int do_relu)
{
    int n = blockIdx.x * 4 + (threadIdx.x >> 6);
    if (n >= N_NODES) return;
    int lane = threadIdx.x & 63;
    int beg = row_ptr[n], end = row_ptr[n + 1];
    float qf = q[(size_t)n * HDIM + lane];
    float m = -1e30f, s = 0.f, acc = 0.f;
    int i = beg;
    for (; i + 2 <= end; i += 2) {
        int s0 = csr_src[i], s1 = csr_src[i + 1];
        float k0 = k[(size_t)s0 * HDIM + lane];
        float k1 = k[(size_t)s1 * HDIM + lane];
        float v0 = v[(size_t)s0 * HDIM + lane];
        float v1 = v[(size_t)s1 * HDIM + lane];
        float p0 = qf * k0, p1 = qf * k1;
        #pragma unroll
        for (int off = 32; off; off >>= 1) {
            p0 += __shfl_xor(p0, off, 64);
            p1 += __shfl_xor(p1, off, 64);
        }
        float a0 = p0 * 0.125f, a1 = p1 * 0.125f;
        float mm = fmaxf(a0, a1);
        float e0 = __expf(a0 - mm), e1 = __expf(a1 - mm);
        float mn = fmaxf(m, mm);
        float sc = __expf(m - mn), sl = __expf(mm - mn);
        s   = s * sc + (e0 + e1) * sl;
        acc = acc * sc + (e0 * v0 + e1 * v1) * sl;
        m = mn;
    }
    if (i < end) {
        int s0 = csr_src[i];
        float k0 = k[(size_t)s0 * HDIM + lane];
        float v0 = v[(size_t)s0 * HDIM + lane];
        float p0 = qf * k0;
        #pragma unroll
        for (int off = 32; off; off >>= 1) p0 += __shfl_xor(p0, off, 64);
        float a0 = p0 * 0.125f;
        float mn = fmaxf(m, a0);
        float sc = __expf(m - mn), e0 = __expf(a0 - mn);
        s = s * sc + e0;
        acc = acc * sc + e0 * v0;
        m = mn;
    }
    float val = (s > 0.f ? acc / s : 0.f) + skip[(size_t)n * HDIM + lane];
    if (do_relu) val = fmaxf(val, 0.f);
    hout[(size_t)n * HDIM + lane] = val;
}

// ---------- mean pool: run-length accumulate (batch sorted) ----------
__global__ __launch_bounds__(256) void pool_kernel(
    const float* __restrict__ h, const int* __restrict__ batch,
    float* __restrict__ sums, float* __restrict__ cnt)
{
    int wid = blockIdx.x * 4 + (threadIdx.x >> 6);
    int n0 = wid * 64;
    if (n0 >= N_NODES) return;
    int lane = threadIdx.x & 63;
    int nend = min(n0 + 64, N_NODES);
    float acc = 0.f;
    int b_cur = batch[n0];
    int run = 0;
    for (int n = n0; n < nend; n++) {
        int b = batch[n];
        if (b != b_cur) {
            atomicAdd(&sums[b_cur * HDIM + lane], acc);
            if (lane == 0) atomicAdd(&cnt[b_cur], (float)run);
            acc = 0.f; run = 0; b_cur = b;
        }
        acc += h[(size_t)n * HDIM + lane];
        run++;
    }
    atomicAdd(&sums[b_cur * HDIM + lane], acc);
    if (lane == 0) atomicAdd(&cnt[b_cur], (float)run);
}

// ---------- head ----------
__global__ void head_kernel(
    const float* __restrict__ sums, const float* __restrict__ cnt,
    const float* __restrict__ Wl, const float* __restrict__ bl,
    float* __restrict__ out)
{
    int tid = threadIdx.x;
    if (tid >= NB * NC) return;
    int b = tid / NC, c = tid % NC;
    float cc = fmaxf(cnt[b], 1.0f);
    float acc = bl[c];
    #pragma unroll
    for (int f = 0; f < HDIM; f++)
        acc += (sums[b * HDIM + f] / cc) * Wl[c * HDIM + f];
    out[tid] = acc;
}

extern "C" void kernel_launch(void* const* d_in, const int* in_sizes, int n_in,
                              void* d_out, int out_size, void* d_ws, size_t ws_size,
                              hipStream_t stream)
{
    const float* x     = (const float*)d_in[0];
    const int*   ei    = (const int*)d_in[1];
    const int*   batch = (const int*)d_in[2];

    const float* W[3][4];
    const float* B[3][4];
    for (int l = 0; l < 3; l++)
        for (int j = 0; j < 4; j++) {
            W[l][j] = (const float*)d_in[3 + l * 8 + j * 2];
            B[l][j] = (const float*)d_in[3 + l * 8 + j * 2 + 1];
        }
    const float* Wl = (const float*)d_in[27];
    const float* bl = (const float*)d_in[28];
    float* out = (float*)d_out;

    const size_t NF = (size_t)N_NODES * HDIM;
    char* w = (char*)d_ws;
    float* h       = (float*)w;  w += NF * 4;
    float* q       = (float*)w;  w += NF * 4;
    float* kbuf    = (float*)w;  w += NF * 4;
    float* v       = (float*)w;  w += NF * 4;
    float* skip    = (float*)w;  w += NF * 4;
    int*   csr_src = (int*)w;    w += (size_t)N_EDGES * 4;
    int*   row_ptr = (int*)w;    w += (size_t)(N_NODES + 1) * 4;
    int*   cursor  = (int*)w;    w += (size_t)N_NODES * 4;
    int*   deg     = (int*)w;    w += (size_t)N_NODES * 4;
    int*   bsum    = (int*)w;    w += (size_t)NBLK_NODES * 4;
    float* sums    = (float*)w;  w += (size_t)NB * HDIM * 4;
    float* cnt     = (float*)w;  w += (size_t)NB * 4;

    const int gemm_gx = (N_NODES + 63) / 64;
    const int edge_gx = (N_EDGES + 255) / 256;
    const int node_gx = (N_NODES + 3) / 4;
    const int pool_gx = (N_NODES + 64 * 4 - 1) / (64 * 4);

    // ----- CSR build (once; edges shared by all 3 layers) -----
    hipMemsetAsync(deg, 0, (size_t)N_NODES * 4, stream);
    count_deg<<<edge_gx, 256, 0, stream>>>(ei, deg);
    deg_block_sum<<<NBLK_NODES, 256, 0, stream>>>(deg, bsum);
    scan_bsum<<<1, 512, 0, stream>>>(bsum, NBLK_NODES);
    write_rowptr<<<NBLK_NODES, 256, 0, stream>>>(deg, bsum, row_ptr, cursor);
    scatter_csr<<<edge_gx, 256, 0, stream>>>(ei, cursor, csr_src);

    for (int l = 0; l < 3; l++) {
        if (l == 0) {
            qkvs_gemm<F_IN><<<dim3(gemm_gx, 4), 256, 0, stream>>>(
                x, W[0][0], B[0][0], W[0][1], B[0][1],
                   W[0][2], B[0][2], W[0][3], B[0][3], q, kbuf, v, skip);
        } else {
            qkvs_gemm<HDIM><<<dim3(gemm_gx, 4), 256, 0, stream>>>(
                h, W[l][0], B[l][0], W[l][1], B[l][1],
                   W[l][2], B[l][2], W[l][3], B[l][3], q, kbuf, v, skip);
        }
        attn_fused<<<node_gx, 256, 0, stream>>>(
            row_ptr, csr_src, q, kbuf, v, skip, h, l < 2 ? 1 : 0);
    }

    hipMemsetAsync(sums, 0, (size_t)NB * HDIM * 4, stream);
    hipMemsetAsync(cnt,  0, (size_t)NB * 4, stream);
    pool_kernel<<<pool_gx, 256, 0, stream>>>(h, batch, sums, cnt);
    head_kernel<<<1, 640, 0, stream>>>(sums, cnt, Wl, bl, out);
}

// Round 5
// 817.220 us; speedup vs baseline: 4.0039x; 1.0417x over previous
//
#include <hip/hip_runtime.h>
#include <math.h>

#define N_NODES 100000
#define N_EDGES 1600000
#define NB 64
#define F_IN 128
#define HDIM 64
#define NC 10
#define NBLK_NODES ((N_NODES + 255) / 256)

// ---------- fused q/k/v/skip GEMM (all 4 mats in one block; X staged once) ----------
// grid.x = ceil(N/64), block = 256
template<int K>
__global__ __launch_bounds__(256) void qkvs_gemm_f(
    const float* __restrict__ xin,
    const float* __restrict__ Wq, const float* __restrict__ bq,
    const float* __restrict__ Wk, const float* __restrict__ bk,
    const float* __restrict__ Wv, const float* __restrict__ bv,
    const float* __restrict__ Ws, const float* __restrict__ bs,
    float* __restrict__ q, float* __restrict__ k,
    float* __restrict__ v, float* __restrict__ sk)
{
    __shared__ float Xs[K][68];    // transposed: Xs[k][row]
    __shared__ float Wt[32][68];   // transposed: Wt[k][col], one 32-chunk at a time

    const int row0 = blockIdx.x * 64;
    const int tid  = threadIdx.x;
    const int tc   = tid & 15;     // col group (4 cols each)
    const int tr   = tid >> 4;     // row group (4 rows each)
    const int lrow = tid >> 2;     // 0..63
    const int lk   = (tid & 3) * 8;

    // stage full X tile (64 rows x K) transposed
    for (int k0 = 0; k0 < K; k0 += 32) {
        int grow = row0 + lrow;
        float tmp[8];
        if (grow < N_NODES) {
            const float* p = xin + (size_t)grow * K + k0 + lk;
            float4 a = *(const float4*)p;
            float4 c = *(const float4*)(p + 4);
            tmp[0]=a.x; tmp[1]=a.y; tmp[2]=a.z; tmp[3]=a.w;
            tmp[4]=c.x; tmp[5]=c.y; tmp[6]=c.z; tmp[7]=c.w;
        } else {
            #pragma unroll
            for (int i = 0; i < 8; i++) tmp[i] = 0.f;
        }
        #pragma unroll
        for (int i = 0; i < 8; i++) Xs[k0 + lk + i][lrow] = tmp[i];
    }

    const float* Wm[4] = {Wq, Wk, Wv, Ws};
    const float* Bm[4] = {bq, bk, bv, bs};
    float*       Om[4] = {q, k, v, sk};

    for (int mat = 0; mat < 4; mat++) {
        float acc[4][4] = {};
        for (int k0 = 0; k0 < K; k0 += 32) {
            __syncthreads();   // protects Xs (first pass) / Wt (prev use)
            {
                const float* pw = Wm[mat] + (size_t)lrow * K + k0 + lk;
                float4 a = *(const float4*)pw;
                float4 c = *(const float4*)(pw + 4);
                float wt[8] = {a.x, a.y, a.z, a.w, c.x, c.y, c.z, c.w};
                #pragma unroll
                for (int i = 0; i < 8; i++) Wt[lk + i][lrow] = wt[i];
            }
            __syncthreads();

            #pragma unroll 8
            for (int kk = 0; kk < 32; kk++) {
                float4 xf = *(const float4*)&Xs[k0 + kk][tr * 4];
                float4 wf = *(const float4*)&Wt[kk][tc * 4];
                float xa[4] = {xf.x, xf.y, xf.z, xf.w};
                float wa[4] = {wf.x, wf.y, wf.z, wf.w};
                #pragma unroll
                for (int i = 0; i < 4; i++)
                    #pragma unroll
                    for (int j = 0; j < 4; j++)
                        acc[i][j] += xa[i] * wa[j];
            }
        }
        float4 bias = *(const float4*)&Bm[mat][tc * 4];
        float ba[4] = {bias.x, bias.y, bias.z, bias.w};
        float* out = Om[mat];
        #pragma unroll
        for (int i = 0; i < 4; i++) {
            int grow = row0 + tr * 4 + i;
            if (grow < N_NODES) {
                float4 r;
                r.x = acc[i][0] + ba[0];
                r.y = acc[i][1] + ba[1];
                r.z = acc[i][2] + ba[2];
                r.w = acc[i][3] + ba[3];
                *(float4*)&out[(size_t)grow * HDIM + tc * 4] = r;
            }
        }
    }
}

// ---------- CSR build ----------
__global__ __launch_bounds__(256) void count_deg(
    const int* __restrict__ ei, int* __restrict__ deg)
{
    int e = blockIdx.x * 256 + threadIdx.x;
    if (e >= N_EDGES) return;
    atomicAdd(&deg[ei[N_EDGES + e]], 1);
}

__global__ __launch_bounds__(256) void deg_block_sum(
    const int* __restrict__ deg, int* __restrict__ bsum)
{
    __shared__ int sh[256];
    int i = blockIdx.x * 256 + threadIdx.x;
    sh[threadIdx.x] = (i < N_NODES) ? deg[i] : 0;
    __syncthreads();
    #pragma unroll
    for (int off = 128; off; off >>= 1) {
        if (threadIdx.x < off) sh[threadIdx.x] += sh[threadIdx.x + off];
        __syncthreads();
    }
    if (threadIdx.x == 0) bsum[blockIdx.x] = sh[0];
}

__global__ __launch_bounds__(512) void scan_bsum(int* __restrict__ bsum, int nb)
{
    __shared__ int sh[512];
    int t = threadIdx.x;
    int v = (t < nb) ? bsum[t] : 0;
    sh[t] = v;
    __syncthreads();
    for (int off = 1; off < 512; off <<= 1) {
        int u = (t >= off) ? sh[t - off] : 0;
        __syncthreads();
        sh[t] += u;
        __syncthreads();
    }
    if (t < nb) bsum[t] = sh[t] - v;   // exclusive
}

__global__ __launch_bounds__(256) void write_rowptr(
    const int* __restrict__ deg, const int* __restrict__ bsum,
    int* __restrict__ row_ptr, int* __restrict__ cursor)
{
    __shared__ int sh[256];
    int i = blockIdx.x * 256 + threadIdx.x;
    int v = (i < N_NODES) ? deg[i] : 0;
    sh[threadIdx.x] = v;
    __syncthreads();
    for (int off = 1; off < 256; off <<= 1) {
        int u = (threadIdx.x >= off) ? sh[threadIdx.x - off] : 0;
        __syncthreads();
        sh[threadIdx.x] += u;
        __syncthreads();
    }
    if (i < N_NODES) {
        int ex = bsum[blockIdx.x] + sh[threadIdx.x] - v;
        row_ptr[i] = ex;
        cursor[i] = ex;
        if (i == N_NODES - 1) row_ptr[N_NODES] = bsum[blockIdx.x] + sh[threadIdx.x];
    }
}

__global__ __launch_bounds__(256) void scatter_csr(
    const int* __restrict__ ei, int* __restrict__ cursor, int* __restrict__ csr_src)
{
    int e = blockIdx.x * 256 + threadIdx.x;
    if (e >= N_EDGES) return;
    int src = ei[e];
    int dst = ei[N_EDGES + e];
    int pos = atomicAdd(&cursor[dst], 1);
    csr_src[pos] = src;
}

// ---------- fused attention: wave per dst, 4 edges/iter, float4 features ----------
// lane = g*16 + t : g = edge slot (0..3), t = feature quad (features 4t..4t+3)
__global__ __launch_bounds__(256) void attn_fused(
    const int* __restrict__ row_ptr, const int* __restrict__ csr_src,
    const float* __restrict__ q, const float* __restrict__ k,
    const float* __restrict__ v, const float* __restrict__ skip,
    float* __restrict__ hout, int do_relu)
{
    int n = blockIdx.x * 4 + (threadIdx.x >> 6);
    if (n >= N_NODES) return;
    int lane = threadIdx.x & 63;
    int g = lane >> 4;
    int t = lane & 15;
    int beg = row_ptr[n], end = row_ptr[n + 1];

    float4 qf = *(const float4*)&q[(size_t)n * HDIM + t * 4];
    float m = -1e30f, s = 0.f;
    float4 acc = make_float4(0.f, 0.f, 0.f, 0.f);

    for (int i = beg; i < end; i += 4) {
        int e = i + g;
        bool valid = (e < end);
        int src = csr_src[valid ? e : beg];
        float4 kf = *(const float4*)&k[(size_t)src * HDIM + t * 4];
        float4 vf = *(const float4*)&v[(size_t)src * HDIM + t * 4];
        float p = qf.x * kf.x + qf.y * kf.y + qf.z * kf.z + qf.w * kf.w;
        p += __shfl_xor(p, 1, 64);
        p += __shfl_xor(p, 2, 64);
        p += __shfl_xor(p, 4, 64);
        p += __shfl_xor(p, 8, 64);
        float a = valid ? p * 0.125f : -INFINITY;
        float mn = fmaxf(m, a);
        float sc = __expf(m - mn);
        float ew = __expf(a - mn);
        s = s * sc + ew;
        acc.x = acc.x * sc + ew * vf.x;
        acc.y = acc.y * sc + ew * vf.y;
        acc.z = acc.z * sc + ew * vf.z;
        acc.w = acc.w * sc + ew * vf.w;
        m = mn;
    }

    // merge the 4 group-local softmax states (lanes l, l^16, l^32)
    #pragma unroll
    for (int off = 16; off <= 32; off <<= 1) {
        float m2 = __shfl_xor(m, off, 64);
        float s2 = __shfl_xor(s, off, 64);
        float ax = __shfl_xor(acc.x, off, 64);
        float ay = __shfl_xor(acc.y, off, 64);
        float az = __shfl_xor(acc.z, off, 64);
        float aw = __shfl_xor(acc.w, off, 64);
        float mn = fmaxf(m, m2);
        float c1 = __expf(m - mn);
        float c2 = __expf(m2 - mn);
        s = s * c1 + s2 * c2;
        acc.x = acc.x * c1 + ax * c2;
        acc.y = acc.y * c1 + ay * c2;
        acc.z = acc.z * c1 + az * c2;
        acc.w = acc.w * c1 + aw * c2;
        m = mn;
    }

    if (g == 0) {
        float inv = (s > 0.f) ? (1.f / s) : 0.f;
        float4 sk4 = *(const float4*)&skip[(size_t)n * HDIM + t * 4];
        float4 val;
        val.x = acc.x * inv + sk4.x;
        val.y = acc.y * inv + sk4.y;
        val.z = acc.z * inv + sk4.z;
        val.w = acc.w * inv + sk4.w;
        if (do_relu) {
            val.x = fmaxf(val.x, 0.f);
            val.y = fmaxf(val.y, 0.f);
            val.z = fmaxf(val.z, 0.f);
            val.w = fmaxf(val.w, 0.f);
        }
        *(float4*)&hout[(size_t)n * HDIM + t * 4] = val;
    }
}

// ---------- mean pool: run-length accumulate (batch sorted) ----------
__global__ __launch_bounds__(256) void pool_kernel(
    const float* __restrict__ h, const int* __restrict__ batch,
    float* __restrict__ sums, float* __restrict__ cnt)
{
    int wid = blockIdx.x * 4 + (threadIdx.x >> 6);
    int n0 = wid * 64;
    if (n0 >= N_NODES) return;
    int lane = threadIdx.x & 63;
    int nend = min(n0 + 64, N_NODES);
    float acc = 0.f;
    int b_cur = batch[n0];
    int run = 0;
    for (int n = n0; n < nend; n++) {
        int b = batch[n];
        if (b != b_cur) {
            atomicAdd(&sums[b_cur * HDIM + lane], acc);
            if (lane == 0) atomicAdd(&cnt[b_cur], (float)run);
            acc = 0.f; run = 0; b_cur = b;
        }
        acc += h[(size_t)n * HDIM + lane];
        run++;
    }
    atomicAdd(&sums[b_cur * HDIM + lane], acc);
    if (lane == 0) atomicAdd(&cnt[b_cur], (float)run);
}

// ---------- head ----------
__global__ void head_kernel(
    const float* __restrict__ sums, const float* __restrict__ cnt,
    const float* __restrict__ Wl, const float* __restrict__ bl,
    float* __restrict__ out)
{
    int tid = threadIdx.x;
    if (tid >= NB * NC) return;
    int b = tid / NC, c = tid % NC;
    float cc = fmaxf(cnt[b], 1.0f);
    float acc = bl[c];
    #pragma unroll
    for (int f = 0; f < HDIM; f++)
        acc += (sums[b * HDIM + f] / cc) * Wl[c * HDIM + f];
    out[tid] = acc;
}

extern "C" void kernel_launch(void* const* d_in, const int* in_sizes, int n_in,
                              void* d_out, int out_size, void* d_ws, size_t ws_size,
                              hipStream_t stream)
{
    const float* x     = (const float*)d_in[0];
    const int*   ei    = (const int*)d_in[1];
    const int*   batch = (const int*)d_in[2];

    const float* W[3][4];
    const float* B[3][4];
    for (int l = 0; l < 3; l++)
        for (int j = 0; j < 4; j++) {
            W[l][j] = (const float*)d_in[3 + l * 8 + j * 2];
            B[l][j] = (const float*)d_in[3 + l * 8 + j * 2 + 1];
        }
    const float* Wl = (const float*)d_in[27];
    const float* bl = (const float*)d_in[28];
    float* out = (float*)d_out;

    const size_t NF = (size_t)N_NODES * HDIM;
    char* w = (char*)d_ws;
    float* h       = (float*)w;  w += NF * 4;
    float* q       = (float*)w;  w += NF * 4;
    float* kbuf    = (float*)w;  w += NF * 4;
    float* v       = (float*)w;  w += NF * 4;
    float* skip    = (float*)w;  w += NF * 4;
    int*   csr_src = (int*)w;    w += (size_t)N_EDGES * 4;
    int*   row_ptr = (int*)w;    w += (size_t)(N_NODES + 1) * 4;
    int*   cursor  = (int*)w;    w += (size_t)N_NODES * 4;
    int*   deg     = (int*)w;    w += (size_t)N_NODES * 4;
    int*   bsum    = (int*)w;    w += (size_t)NBLK_NODES * 4;
    float* sums    = (float*)w;  w += (size_t)NB * HDIM * 4;
    float* cnt     = (float*)w;  w += (size_t)NB * 4;

    const int gemm_gx = (N_NODES + 63) / 64;
    const int edge_gx = (N_EDGES + 255) / 256;
    const int node_gx = (N_NODES + 3) / 4;
    const int pool_gx = (N_NODES + 64 * 4 - 1) / (64 * 4);

    // ----- CSR build (once; edges shared by all 3 layers) -----
    hipMemsetAsync(deg, 0, (size_t)N_NODES * 4, stream);
    count_deg<<<edge_gx, 256, 0, stream>>>(ei, deg);
    deg_block_sum<<<NBLK_NODES, 256, 0, stream>>>(deg, bsum);
    scan_bsum<<<1, 512, 0, stream>>>(bsum, NBLK_NODES);
    write_rowptr<<<NBLK_NODES, 256, 0, stream>>>(deg, bsum, row_ptr, cursor);
    scatter_csr<<<edge_gx, 256, 0, stream>>>(ei, cursor, csr_src);

    for (int l = 0; l < 3; l++) {
        if (l == 0) {
            qkvs_gemm_f<F_IN><<<gemm_gx, 256, 0, stream>>>(
                x, W[0][0], B[0][0], W[0][1], B[0][1],
                   W[0][2], B[0][2], W[0][3], B[0][3], q, kbuf, v, skip);
        } else {
            qkvs_gemm_f<HDIM><<<gemm_gx, 256, 0, stream>>>(
                h, W[l][0], B[l][0], W[l][1], B[l][1],
                   W[l][2], B[l][2], W[l][3], B[l][3], q, kbuf, v, skip);
        }
        attn_fused<<<node_gx, 256, 0, stream>>>(
            row_ptr, csr_src, q, kbuf, v, skip, h, l < 2 ? 1 : 0);
    }

    hipMemsetAsync(sums, 0, (size_t)NB * HDIM * 4, stream);
    hipMemsetAsync(cnt,  0, (size_t)NB * 4, stream);
    pool_kernel<<<pool_gx, 256, 0, stream>>>(h, batch, sums, cnt);
    head_kernel<<<1, 640, 0, stream>>>(sums, cnt, Wl, bl, out);
}

// Round 6
// 735.696 us; speedup vs baseline: 4.4475x; 1.1108x over previous
//
#include <hip/hip_runtime.h>
#include <math.h>

#define N_NODES 100000
#define N_EDGES 1600000
#define NB 64
#define F_IN 128
#define HDIM 64
#define NC 10
#define NBLK_NODES ((N_NODES + 255) / 256)

#define BSHIFT 9
#define BUCKET_NODES (1 << BSHIFT)                          // 512
#define NBUCK ((N_NODES + BUCKET_NODES - 1) >> BSHIFT)      // 196
#define EW_CHUNK 4096
#define EW_GRID ((N_EDGES + EW_CHUNK - 1) / EW_CHUNK)       // 391

// ---------- fused q/k/v/skip GEMM (X staged once, full-W staging per mat) ----------
// grid.x = ceil(N/64), block = 256
template<int K>
__global__ __launch_bounds__(256) void qkvs_gemm_f(
    const float* __restrict__ xin,
    const float* __restrict__ Wq, const float* __restrict__ bq,
    const float* __restrict__ Wk, const float* __restrict__ bk,
    const float* __restrict__ Wv, const float* __restrict__ bv,
    const float* __restrict__ Ws, const float* __restrict__ bs,
    float* __restrict__ q, float* __restrict__ k,
    float* __restrict__ v, float* __restrict__ sk)
{
    __shared__ float Xs[K][68];    // transposed: Xs[k][row]
    __shared__ float Wt[K][68];    // transposed: Wt[k][col], full K for one mat

    const int row0 = blockIdx.x * 64;
    const int tid  = threadIdx.x;
    const int tc   = tid & 15;     // col group (4 cols each)
    const int tr   = tid >> 4;     // row group (4 rows each)
    const int lrow = tid >> 2;     // 0..63
    const int lk   = (tid & 3) * 8;

    // stage full X tile (64 rows x K) transposed
    for (int k0 = 0; k0 < K; k0 += 32) {
        int grow = row0 + lrow;
        float tmp[8];
        if (grow < N_NODES) {
            const float* p = xin + (size_t)grow * K + k0 + lk;
            float4 a = *(const float4*)p;
            float4 c = *(const float4*)(p + 4);
            tmp[0]=a.x; tmp[1]=a.y; tmp[2]=a.z; tmp[3]=a.w;
            tmp[4]=c.x; tmp[5]=c.y; tmp[6]=c.z; tmp[7]=c.w;
        } else {
            #pragma unroll
            for (int i = 0; i < 8; i++) tmp[i] = 0.f;
        }
        #pragma unroll
        for (int i = 0; i < 8; i++) Xs[k0 + lk + i][lrow] = tmp[i];
    }

    const float* Wm[4] = {Wq, Wk, Wv, Ws};
    const float* Bm[4] = {bq, bk, bv, bs};
    float*       Om[4] = {q, k, v, sk};

    for (int mat = 0; mat < 4; mat++) {
        if (mat) __syncthreads();          // protect Wt from previous compute
        // stage full W (64 out-cols x K) transposed
        for (int k0 = 0; k0 < K; k0 += 32) {
            const float* pw = Wm[mat] + (size_t)lrow * K + k0 + lk;
            float4 a = *(const float4*)pw;
            float4 c = *(const float4*)(pw + 4);
            float wt[8] = {a.x, a.y, a.z, a.w, c.x, c.y, c.z, c.w};
            #pragma unroll
            for (int i = 0; i < 8; i++) Wt[k0 + lk + i][lrow] = wt[i];
        }
        __syncthreads();                   // covers Xs (first mat) + Wt

        float acc[4][4] = {};
        #pragma unroll 8
        for (int kk = 0; kk < K; kk++) {
            float4 xf = *(const float4*)&Xs[kk][tr * 4];
            float4 wf = *(const float4*)&Wt[kk][tc * 4];
            float xa[4] = {xf.x, xf.y, xf.z, xf.w};
            float wa[4] = {wf.x, wf.y, wf.z, wf.w};
            #pragma unroll
            for (int i = 0; i < 4; i++)
                #pragma unroll
                for (int j = 0; j < 4; j++)
                    acc[i][j] += xa[i] * wa[j];
        }

        float4 bias = *(const float4*)&Bm[mat][tc * 4];
        float ba[4] = {bias.x, bias.y, bias.z, bias.w};
        float* out = Om[mat];
        #pragma unroll
        for (int i = 0; i < 4; i++) {
            int grow = row0 + tr * 4 + i;
            if (grow < N_NODES) {
                float4 r;
                r.x = acc[i][0] + ba[0];
                r.y = acc[i][1] + ba[1];
                r.z = acc[i][2] + ba[2];
                r.w = acc[i][3] + ba[3];
                *(float4*)&out[(size_t)grow * HDIM + tc * 4] = r;
            }
        }
    }
}

// ---------- CSR build, stage 1: per-dst degree + per-bucket counts ----------
__global__ __launch_bounds__(256) void count_deg_bucket(
    const int* __restrict__ ei, int* __restrict__ deg, int* __restrict__ bcnt)
{
    __shared__ int hist[NBUCK];
    for (int i = threadIdx.x; i < NBUCK; i += 256) hist[i] = 0;
    __syncthreads();
    int e0 = blockIdx.x * EW_CHUNK;
    #pragma unroll
    for (int i = 0; i < EW_CHUNK / 256; i++) {
        int e = e0 + i * 256 + threadIdx.x;
        if (e < N_EDGES) {
            int dst = ei[N_EDGES + e];
            atomicAdd(&deg[dst], 1);
            atomicAdd(&hist[dst >> BSHIFT], 1);
        }
    }
    __syncthreads();
    for (int i = threadIdx.x; i < NBUCK; i += 256)
        if (hist[i]) atomicAdd(&bcnt[i], hist[i]);
}

// ---------- row_ptr scan (3 kernels) ----------
__global__ __launch_bounds__(256) void deg_block_sum(
    const int* __restrict__ deg, int* __restrict__ bsum)
{
    __shared__ int sh[256];
    int i = blockIdx.x * 256 + threadIdx.x;
    sh[threadIdx.x] = (i < N_NODES) ? deg[i] : 0;
    __syncthreads();
    #pragma unroll
    for (int off = 128; off; off >>= 1) {
        if (threadIdx.x < off) sh[threadIdx.x] += sh[threadIdx.x + off];
        __syncthreads();
    }
    if (threadIdx.x == 0) bsum[blockIdx.x] = sh[0];
}

__global__ __launch_bounds__(512) void scan_bsum(int* __restrict__ bsum, int nb)
{
    __shared__ int sh[512];
    int t = threadIdx.x;
    int v = (t < nb) ? bsum[t] : 0;
    sh[t] = v;
    __syncthreads();
    for (int off = 1; off < 512; off <<= 1) {
        int u = (t >= off) ? sh[t - off] : 0;
        __syncthreads();
        sh[t] += u;
        __syncthreads();
    }
    if (t < nb) bsum[t] = sh[t] - v;   // exclusive
}

__global__ __launch_bounds__(256) void write_rowptr(
    const int* __restrict__ deg, const int* __restrict__ bsum,
    int* __restrict__ row_ptr)
{
    __shared__ int sh[256];
    int i = blockIdx.x * 256 + threadIdx.x;
    int v = (i < N_NODES) ? deg[i] : 0;
    sh[threadIdx.x] = v;
    __syncthreads();
    for (int off = 1; off < 256; off <<= 1) {
        int u = (threadIdx.x >= off) ? sh[threadIdx.x - off] : 0;
        __syncthreads();
        sh[threadIdx.x] += u;
        __syncthreads();
    }
    if (i < N_NODES) {
        int ex = bsum[blockIdx.x] + sh[threadIdx.x] - v;
        row_ptr[i] = ex;
        if (i == N_NODES - 1) row_ptr[N_NODES] = bsum[blockIdx.x] + sh[threadIdx.x];
    }
}

// ---------- CSR build, stage 2: bucket base scan (196 values, one block) ----------
__global__ __launch_bounds__(256) void scan_bucket(
    const int* __restrict__ bcnt, int* __restrict__ bbase, int* __restrict__ gcursor)
{
    __shared__ int sh[256];
    int t = threadIdx.x;
    int v = (t < NBUCK) ? bcnt[t] : 0;
    sh[t] = v;
    __syncthreads();
    for (int off = 1; off < 256; off <<= 1) {
        int u = (t >= off) ? sh[t - off] : 0;
        __syncthreads();
        sh[t] += u;
        __syncthreads();
    }
    if (t < NBUCK) { bbase[t] = sh[t] - v; gcursor[t] = sh[t] - v; }
}

// ---------- CSR build, stage 3: scatter edges into bucket-ordered array ----------
__global__ __launch_bounds__(256) void bucket_scatter(
    const int* __restrict__ ei, int* __restrict__ gcursor, int2* __restrict__ bedge)
{
    __shared__ int hist[NBUCK];
    __shared__ int base[NBUCK];
    for (int i = threadIdx.x; i < NBUCK; i += 256) hist[i] = 0;
    __syncthreads();
    int e0 = blockIdx.x * EW_CHUNK;
    #pragma unroll
    for (int i = 0; i < EW_CHUNK / 256; i++) {
        int e = e0 + i * 256 + threadIdx.x;
        if (e < N_EDGES) atomicAdd(&hist[ei[N_EDGES + e] >> BSHIFT], 1);
    }
    __syncthreads();
    for (int i = threadIdx.x; i < NBUCK; i += 256)
        base[i] = hist[i] ? atomicAdd(&gcursor[i], hist[i]) : 0;
    __syncthreads();
    for (int i = threadIdx.x; i < NBUCK; i += 256) hist[i] = 0;
    __syncthreads();
    #pragma unroll
    for (int i = 0; i < EW_CHUNK / 256; i++) {
        int e = e0 + i * 256 + threadIdx.x;
        if (e < N_EDGES) {
            int src = ei[e];
            int dst = ei[N_EDGES + e];
            int b = dst >> BSHIFT;
            int pos = base[b] + atomicAdd(&hist[b], 1);
            bedge[pos] = make_int2(src, dst);
        }
    }
}

// ---------- CSR build, stage 4: one WG per bucket, LDS cursors ----------
__global__ __launch_bounds__(256) void csr_from_buckets(
    const int2* __restrict__ bedge, const int* __restrict__ bbase,
    const int* __restrict__ bcnt, const int* __restrict__ row_ptr,
    int* __restrict__ csr_src)
{
    __shared__ int cur[BUCKET_NODES];
    int b = blockIdx.x;
    int dst0 = b << BSHIFT;
    for (int i = threadIdx.x; i < BUCKET_NODES; i += 256) {
        int d = dst0 + i;
        cur[i] = (d < N_NODES) ? row_ptr[d] : 0;
    }
    __syncthreads();
    int beg = bbase[b], cnt = bcnt[b];
    for (int i = threadIdx.x; i < cnt; i += 256) {
        int2 ed = bedge[beg + i];
        int pos = atomicAdd(&cur[ed.y - dst0], 1);
        csr_src[pos] = ed.x;
    }
}

// ---------- fused attention: wave per dst, 4 edges/iter, float4 features ----------
__global__ __launch_bounds__(256) void attn_fused(
    const int* __restrict__ row_ptr, const int* __restrict__ csr_src,
    const float* __restrict__ q, const float* __restrict__ k,
    const float* __restrict__ v, const float* __restrict__ skip,
    float* __restrict__ hout, int do_relu)
{
    int n = blockIdx.x * 4 + (threadIdx.x >> 6);
    if (n >= N_NODES) return;
    int lane = threadIdx.x & 63;
    int g = lane >> 4;
    int t = lane & 15;
    int beg = row_ptr[n], end = row_ptr[n + 1];

    float4 qf = *(const float4*)&q[(size_t)n * HDIM + t * 4];
    float m = -1e30f, s = 0.f;
    float4 acc = make_float4(0.f, 0.f, 0.f, 0.f);

    for (int i = beg; i < end; i += 4) {
        int e = i + g;
        bool valid = (e < end);
        int src = csr_src[valid ? e : beg];
        float4 kf = *(const float4*)&k[(size_t)src * HDIM + t * 4];
        float4 vf = *(const float4*)&v[(size_t)src * HDIM + t * 4];
        float p = qf.x * kf.x + qf.y * kf.y + qf.z * kf.z + qf.w * kf.w;
        p += __shfl_xor(p, 1, 64);
        p += __shfl_xor(p, 2, 64);
        p += __shfl_xor(p, 4, 64);
        p += __shfl_xor(p, 8, 64);
        float a = valid ? p * 0.125f : -INFINITY;
        float mn = fmaxf(m, a);
        float sc = __expf(m - mn);
        float ew = __expf(a - mn);
        s = s * sc + ew;
        acc.x = acc.x * sc + ew * vf.x;
        acc.y = acc.y * sc + ew * vf.y;
        acc.z = acc.z * sc + ew * vf.z;
        acc.w = acc.w * sc + ew * vf.w;
        m = mn;
    }

    #pragma unroll
    for (int off = 16; off <= 32; off <<= 1) {
        float m2 = __shfl_xor(m, off, 64);
        float s2 = __shfl_xor(s, off, 64);
        float ax = __shfl_xor(acc.x, off, 64);
        float ay = __shfl_xor(acc.y, off, 64);
        float az = __shfl_xor(acc.z, off, 64);
        float aw = __shfl_xor(acc.w, off, 64);
        float mn = fmaxf(m, m2);
        float c1 = __expf(m - mn);
        float c2 = __expf(m2 - mn);
        s = s * c1 + s2 * c2;
        acc.x = acc.x * c1 + ax * c2;
        acc.y = acc.y * c1 + ay * c2;
        acc.z = acc.z * c1 + az * c2;
        acc.w = acc.w * c1 + aw * c2;
        m = mn;
    }

    if (g == 0) {
        float inv = (s > 0.f) ? (1.f / s) : 0.f;
        float4 sk4 = *(const float4*)&skip[(size_t)n * HDIM + t * 4];
        float4 val;
        val.x = acc.x * inv + sk4.x;
        val.y = acc.y * inv + sk4.y;
        val.z = acc.z * inv + sk4.z;
        val.w = acc.w * inv + sk4.w;
        if (do_relu) {
            val.x = fmaxf(val.x, 0.f);
            val.y = fmaxf(val.y, 0.f);
            val.z = fmaxf(val.z, 0.f);
            val.w = fmaxf(val.w, 0.f);
        }
        *(float4*)&hout[(size_t)n * HDIM + t * 4] = val;
    }
}

// ---------- mean pool: run-length accumulate (batch sorted) ----------
__global__ __launch_bounds__(256) void pool_kernel(
    const float* __restrict__ h, const int* __restrict__ batch,
    float* __restrict__ sums, float* __restrict__ cnt)
{
    int wid = blockIdx.x * 4 + (threadIdx.x >> 6);
    int n0 = wid * 64;
    if (n0 >= N_NODES) return;
    int lane = threadIdx.x & 63;
    int nend = min(n0 + 64, N_NODES);
    float acc = 0.f;
    int b_cur = batch[n0];
    int run = 0;
    for (int n = n0; n < nend; n++) {
        int b = batch[n];
        if (b != b_cur) {
            atomicAdd(&sums[b_cur * HDIM + lane], acc);
            if (lane == 0) atomicAdd(&cnt[b_cur], (float)run);
            acc = 0.f; run = 0; b_cur = b;
        }
        acc += h[(size_t)n * HDIM + lane];
        run++;
    }
    atomicAdd(&sums[b_cur * HDIM + lane], acc);
    if (lane == 0) atomicAdd(&cnt[b_cur], (float)run);
}

// ---------- head ----------
__global__ void head_kernel(
    const float* __restrict__ sums, const float* __restrict__ cnt,
    const float* __restrict__ Wl, const float* __restrict__ bl,
    float* __restrict__ out)
{
    int tid = threadIdx.x;
    if (tid >= NB * NC) return;
    int b = tid / NC, c = tid % NC;
    float cc = fmaxf(cnt[b], 1.0f);
    float acc = bl[c];
    #pragma unroll
    for (int f = 0; f < HDIM; f++)
        acc += (sums[b * HDIM + f] / cc) * Wl[c * HDIM + f];
    out[tid] = acc;
}

extern "C" void kernel_launch(void* const* d_in, const int* in_sizes, int n_in,
                              void* d_out, int out_size, void* d_ws, size_t ws_size,
                              hipStream_t stream)
{
    const float* x     = (const float*)d_in[0];
    const int*   ei    = (const int*)d_in[1];
    const int*   batch = (const int*)d_in[2];

    const float* W[3][4];
    const float* B[3][4];
    for (int l = 0; l < 3; l++)
        for (int j = 0; j < 4; j++) {
            W[l][j] = (const float*)d_in[3 + l * 8 + j * 2];
            B[l][j] = (const float*)d_in[3 + l * 8 + j * 2 + 1];
        }
    const float* Wl = (const float*)d_in[27];
    const float* bl = (const float*)d_in[28];
    float* out = (float*)d_out;

    const size_t NF = (size_t)N_NODES * HDIM;
    char* w = (char*)d_ws;
    float* h       = (float*)w;  w += NF * 4;
    float* q       = (float*)w;  w += NF * 4;
    float* kbuf    = (float*)w;  w += NF * 4;
    float* v       = (float*)w;  w += NF * 4;
    float* skip    = (float*)w;  w += NF * 4;
    int*   csr_src = (int*)w;    w += (size_t)N_EDGES * 4;
    int2*  bedge   = (int2*)w;   w += (size_t)N_EDGES * 8;
    int*   row_ptr = (int*)w;    w += (size_t)(N_NODES + 1) * 4;
    int*   deg     = (int*)w;    w += (size_t)N_NODES * 4;
    int*   bcnt    = (int*)w;    w += (size_t)NBUCK * 4;     // adjacent to deg: one memset
    int*   bbase   = (int*)w;    w += (size_t)NBUCK * 4;
    int*   gcursor = (int*)w;    w += (size_t)NBUCK * 4;
    int*   bsum    = (int*)w;    w += (size_t)NBLK_NODES * 4;
    float* sums    = (float*)w;  w += (size_t)NB * HDIM * 4;
    float* cnt     = (float*)w;  w += (size_t)NB * 4;

    const int gemm_gx = (N_NODES + 63) / 64;
    const int node_gx = (N_NODES + 3) / 4;
    const int pool_gx = (N_NODES + 64 * 4 - 1) / (64 * 4);

    // ----- CSR build via LDS-staged counting sort (once; shared by all layers) -----
    hipMemsetAsync(deg, 0, (size_t)(N_NODES + NBUCK) * 4, stream);   // deg + bcnt
    count_deg_bucket<<<EW_GRID, 256, 0, stream>>>(ei, deg, bcnt);
    deg_block_sum<<<NBLK_NODES, 256, 0, stream>>>(deg, bsum);
    scan_bsum<<<1, 512, 0, stream>>>(bsum, NBLK_NODES);
    write_rowptr<<<NBLK_NODES, 256, 0, stream>>>(deg, bsum, row_ptr);
    scan_bucket<<<1, 256, 0, stream>>>(bcnt, bbase, gcursor);
    bucket_scatter<<<EW_GRID, 256, 0, stream>>>(ei, gcursor, bedge);
    csr_from_buckets<<<NBUCK, 256, 0, stream>>>(bedge, bbase, bcnt, row_ptr, csr_src);

    for (int l = 0; l < 3; l++) {
        if (l == 0) {
            qkvs_gemm_f<F_IN><<<gemm_gx, 256, 0, stream>>>(
                x, W[0][0], B[0][0], W[0][1], B[0][1],
                   W[0][2], B[0][2], W[0][3], B[0][3], q, kbuf, v, skip);
        } else {
            qkvs_gemm_f<HDIM><<<gemm_gx, 256, 0, stream>>>(
                h, W[l][0], B[l][0], W[l][1], B[l][1],
                   W[l][2], B[l][2], W[l][3], B[l][3], q, kbuf, v, skip);
        }
        attn_fused<<<node_gx, 256, 0, stream>>>(
            row_ptr, csr_src, q, kbuf, v, skip, h, l < 2 ? 1 : 0);
    }

    hipMemsetAsync(sums, 0, (size_t)NB * HDIM * 4, stream);
    hipMemsetAsync(cnt,  0, (size_t)NB * 4, stream);
    pool_kernel<<<pool_gx, 256, 0, stream>>>(h, batch, sums, cnt);
    head_kernel<<<1, 640, 0, stream>>>(sums, cnt, Wl, bl, out);
}